// Round 1
// 3710.958 us; speedup vs baseline: 1.0256x; 1.0256x over previous
//
#include <hip/hip_runtime.h>
#include <hip/hip_bf16.h>

// Persistent bidirectional LSTM for MI355X. B=32, T=512, H=512.
// 128 persistent WGs (2 dirs x 64), fp16 weight fragments stationary in VGPRs.
//
// R4 post-mortem: 7.4 us/step, MfmaUtil 1.4% -> still latency-bound on the
// step barrier. Hop arithmetic accounts for ~2 us/step; the ~5 us residual is
// attributed to the single counter line per (dir,step): 64 device-scope RMWs
// serializing at one L3 bank while 64 tid0 pollers hammer the same line with
// sc1 reads (R3's poll storm surviving at reduced scale).
// R5: per-producer flag words. Each (dir,step) slot = 64 ints (4 lines),
//   ring-addressed (never reused -> no reset, no staleness).
//   Producer: one relaxed agent STORE (no RMW) to its own word after the
//   vmcnt(0)-draining barrier. Consumer: wave 0's 64 lanes spin one-flag-per-
//   lane (one coalesced load per iteration over 4 lines); exec-mask retires
//   lanes as flags land; barrier broadcasts. Arrival is parallel, detection
//   <=1 RTT after the last store, zero RMW traffic.
// Modes: 0 = flag ring (preferred), 1 = counter ring (R4, ws-size middle
//   tier), 2 = counter dbuf (small-ws fallback, unchanged from R4).

#define HDIM 512
#define TDIM 512
#define BDIM 32
#define NWG  64     // workgroups per direction
#define NTHR 256
#define CSTRIDE 16  // ints per counter slot (64 B line padding), modes 1/2
#define FLAGN 64    // one flag word per producer WG, mode 0 (256 B per slot)
#define SLOTS (TDIM + 1)

typedef float f32x4 __attribute__((ext_vector_type(4)));
typedef _Float16 half8 __attribute__((ext_vector_type(8)));
typedef unsigned long long u64x2 __attribute__((ext_vector_type(2)));

#define SLICE_INTS (BDIM * HDIM / 2)   // 8192 ints = 32 KB per (step,dir) slice

__device__ __forceinline__ float sigm(float x) { return 1.f / (1.f + __expf(-x)); }
__device__ __forceinline__ float tanh_f(float x) { return 1.f - 2.f / (__expf(2.f * x) + 1.f); }

// ws layout mode 0: [0, 262656): flags, int flg[(d*SLOTS+s)*FLAGN + w].
//                   [262656,...): hbuf ring slices [t][dir][B][H/2], 2xfp16/int.
// ws layout modes 1/2: [0, 65664): counters int cnt[(d*SLOTS+s)*CSTRIDE]; hbuf after.
__global__ void init_ws_kernel(int* __restrict__ sync, int* __restrict__ hbuf_i,
                               int nzero) {
  int i = blockIdx.x * blockDim.x + threadIdx.x;
  int n = blockDim.x * gridDim.x;
  for (int j = i; j < nzero; j += n)
    __hip_atomic_store(sync + j, 0, __ATOMIC_RELAXED, __HIP_MEMORY_SCOPE_AGENT);
  // slice 0 (both dirs) must be zeros (h0 = 0): first 2*SLICE_INTS ints.
  for (int j = i; j < 2 * SLICE_INTS; j += n)
    __hip_atomic_store(hbuf_i + j, 0, __ATOMIC_RELAXED, __HIP_MEMORY_SCOPE_AGENT);
}

template <int MODE>  // 0 = flag ring, 1 = counter ring, 2 = counter dbuf
__global__ __launch_bounds__(NTHR, 1)
void lstm_kernel(const float* __restrict__ x,
                 const float* __restrict__ WihF, const float* __restrict__ WhhF,
                 const float* __restrict__ bihF, const float* __restrict__ bhhF,
                 const float* __restrict__ WihB, const float* __restrict__ WhhB,
                 const float* __restrict__ bihB, const float* __restrict__ bhhB,
                 float* __restrict__ out,
                 int* __restrict__ sync, int* __restrict__ hbuf) {
  constexpr bool RING = (MODE < 2);
  const int blk = blockIdx.x;
  const int d = blk & 1;    // direction
  const int w = blk >> 1;   // 0..63: owns h-cols [w*8, w*8+8)
  const int tid = threadIdx.x;
  const int lane = tid & 63;
  const int wv = tid >> 6;  // wave 0..3
  const int nt = wv >> 1;   // n-tile (16 gate-cols each)
  const int kh = wv & 1;    // k-half (8 kblocks of 32)

  const float* Wih = d ? WihB : WihF;
  const float* Whh = d ? WhhB : WhhF;
  const float* bih = d ? bihB : bihF;
  const float* bhh = d ? bhhB : bhhF;

  // MFMA 16x16x32 lane roles. A: [m=lane&15][k=quad*8+j]; B: [k=quad*8+j][n=lane&15]
  // C/D: col=lane&15, row=(lane>>4)*4+reg  (m89-verified layouts)
  const int nn = lane & 15;
  const int quad = lane >> 4;
  const int n32 = nt * 16 + nn;        // col within WG's 32 gate-cols
  const int gg = n32 >> 3;             // gate 0..3 (i,f,g,o)
  const int jj = n32 & 7;              // h-col within slice
  const int gc = gg * HDIM + w * 8 + jj;  // global gate-col 0..2047

  // ---- stationary weight fragments (fp16 in VGPRs): 8 kblocks x 2 matrices ----
  half8 wihf[8], whhf[8];
#pragma unroll
  for (int kbi = 0; kbi < 8; ++kbi) {
    const int k0 = (kh * 8 + kbi) * 32 + quad * 8;
    const f32x4* pi = (const f32x4*)(Wih + (size_t)gc * HDIM + k0);
    const f32x4* ph = (const f32x4*)(Whh + (size_t)gc * HDIM + k0);
    f32x4 i0 = pi[0], i1 = pi[1], h0 = ph[0], h1 = ph[1];
    half8 a, b;
#pragma unroll
    for (int j = 0; j < 4; ++j) {
      a[j] = (_Float16)i0[j]; a[4 + j] = (_Float16)i1[j];
      b[j] = (_Float16)h0[j]; b[4 + j] = (_Float16)h1[j];
    }
    wihf[kbi] = a; whhf[kbi] = b;
  }
  // Bias seeded by the kh==0 wave ONLY.
  const float bseed = kh ? 0.f : (bih[gc] + bhh[gc]);

  // cell-update role: one (batch, h-col) per thread; c stays in a register
  const int cb = tid >> 3;
  const int cj = tid & 7;
  const int cmt = cb >> 4;
  const int creg = cb & 3;
  const int crow = (cb & 15) >> 2;
  float c = 0.f;

  __shared__ f32x4 part[8][64];  // [ (nt*2+kh)*2+mt ][lane] partial accs

  const int tstep = d ? -1 : 1;
  int tx = d ? (TDIM - 1) : 0;

  for (int s = 0; s < TDIM; ++s, tx += tstep) {
    f32x4 acc0 = {bseed, bseed, bseed, bseed};
    f32x4 acc1 = acc0;

    // ---- x phase: no cross-WG dependence; overlaps other WGs' step s-1 ----
#pragma unroll
    for (int kbi = 0; kbi < 8; ++kbi) {
      const int k0 = (kh * 8 + kbi) * 32 + quad * 8;
      {
        const f32x4* px = (const f32x4*)(x + ((size_t)nn * TDIM + tx) * HDIM + k0);
        f32x4 u0 = px[0], u1 = px[1];
        half8 ax;
#pragma unroll
        for (int j = 0; j < 4; ++j) { ax[j] = (_Float16)u0[j]; ax[4 + j] = (_Float16)u1[j]; }
        acc0 = __builtin_amdgcn_mfma_f32_16x16x32_f16(ax, wihf[kbi], acc0, 0, 0, 0);
      }
      {
        const f32x4* px = (const f32x4*)(x + ((size_t)(16 + nn) * TDIM + tx) * HDIM + k0);
        f32x4 u0 = px[0], u1 = px[1];
        half8 ax;
#pragma unroll
        for (int j = 0; j < 4; ++j) { ax[j] = (_Float16)u0[j]; ax[4 + j] = (_Float16)u1[j]; }
        acc1 = __builtin_amdgcn_mfma_f32_16x16x32_f16(ax, wihf[kbi], acc1, 0, 0, 0);
      }
    }

    // ---- wait for slice s ----
    if (s > 0) {
      if (MODE == 0) {
        // 64 lanes of wave 0 spin on 64 per-producer flags (4 lines total).
        // Exec-mask retires lanes as their flag lands; no shared-line RMWs.
        if (wv == 0) {
          const int* pf = sync + (size_t)(d * SLOTS + s) * FLAGN + lane;
          while (__hip_atomic_load(pf, __ATOMIC_RELAXED, __HIP_MEMORY_SCOPE_AGENT) == 0) {}
        }
      } else {
        if (tid == 0) {
          const int* pc = sync + (size_t)(d * SLOTS + s) * CSTRIDE;
          while (__hip_atomic_load(pc, __ATOMIC_RELAXED, __HIP_MEMORY_SCOPE_AGENT) < NWG) {}
        }
      }
      __syncthreads();  // broadcast + compiler barrier (no hoisting of h loads)
    }

    // ---- h phase ----
    if (RING) {
      // cached loads; addresses unique per step -> no staleness possible.
      const _Float16* hb =
          (const _Float16*)(hbuf + ((size_t)s * 2 + d) * SLICE_INTS);
#pragma unroll
      for (int kbi = 0; kbi < 8; ++kbi) {
        const int k0 = (kh * 8 + kbi) * 32 + quad * 8;
        half8 a0 = *(const half8*)(hb + nn * HDIM + k0);
        acc0 = __builtin_amdgcn_mfma_f32_16x16x32_f16(a0, whhf[kbi], acc0, 0, 0, 0);
        half8 a1 = *(const half8*)(hb + (16 + nn) * HDIM + k0);
        acc1 = __builtin_amdgcn_mfma_f32_16x16x32_f16(a1, whhf[kbi], acc1, 0, 0, 0);
      }
    } else {
      // bypass loads (sc0/sc1) from the coherence point; double buffer.
      const unsigned long long* hb = (const unsigned long long*)(
          hbuf + ((size_t)(s & 1) * 2 + d) * SLICE_INTS);
#pragma unroll
      for (int kbi = 0; kbi < 8; ++kbi) {
        const int k0 = (kh * 8 + kbi) * 32 + quad * 8;  // fp16 idx; /4 -> u64 idx
        {
          const unsigned long long* p = hb + (nn * (HDIM / 4) + (k0 >> 2));
          u64x2 q;
          q[0] = __hip_atomic_load(p, __ATOMIC_RELAXED, __HIP_MEMORY_SCOPE_AGENT);
          q[1] = __hip_atomic_load(p + 1, __ATOMIC_RELAXED, __HIP_MEMORY_SCOPE_AGENT);
          half8 a0 = __builtin_bit_cast(half8, q);
          acc0 = __builtin_amdgcn_mfma_f32_16x16x32_f16(a0, whhf[kbi], acc0, 0, 0, 0);
        }
        {
          const unsigned long long* p = hb + ((16 + nn) * (HDIM / 4) + (k0 >> 2));
          u64x2 q;
          q[0] = __hip_atomic_load(p, __ATOMIC_RELAXED, __HIP_MEMORY_SCOPE_AGENT);
          q[1] = __hip_atomic_load(p + 1, __ATOMIC_RELAXED, __HIP_MEMORY_SCOPE_AGENT);
          half8 a1 = __builtin_bit_cast(half8, q);
          acc1 = __builtin_amdgcn_mfma_f32_16x16x32_f16(a1, whhf[kbi], acc1, 0, 0, 0);
        }
      }
    }

    // ---- cross-wave (k-half) reduction via LDS ----
    part[wv * 2 + 0][lane] = acc0;
    part[wv * 2 + 1][lane] = acc1;
    __syncthreads();

    // ---- cell update: thread (cb, cj) gathers its 4 gates ----
    float gv[4];
#pragma unroll
    for (int g4 = 0; g4 < 4; ++g4) {
      const int n32g = g4 * 8 + cj;
      const int ntg = n32g >> 4;
      const int ng = n32g & 15;
      const int lg = (crow << 4) | ng;
      f32x4 p0 = part[(ntg * 2 + 0) * 2 + cmt][lg];
      f32x4 p1 = part[(ntg * 2 + 1) * 2 + cmt][lg];
      gv[g4] = p0[creg] + p1[creg];
    }
    const float ig = sigm(gv[0]);
    const float fg = sigm(gv[1]);
    const float gt = tanh_f(gv[2]);
    const float og = sigm(gv[3]);
    c = fg * c + ig * gt;
    const float h = og * tanh_f(c);

    // ---- publish h: pack 2xfp16 per int, even lane of each pair stores ----
    const float hn = __shfl_xor(h, 1);  // neighbor's h (adjacent cj)
    {
      const size_t tdst = RING ? (size_t)(s + 1) : (size_t)((s + 1) & 1);
      int* hw = hbuf + (tdst * 2 + d) * SLICE_INTS;
      if (!(tid & 1)) {
        const unsigned lo = (unsigned)__builtin_bit_cast(unsigned short, (_Float16)h);
        const unsigned hi = (unsigned)__builtin_bit_cast(unsigned short, (_Float16)hn);
        const int packed = (int)(lo | (hi << 16));
        __hip_atomic_store(hw + cb * (HDIM / 2) + ((w * 8 + cj) >> 1), packed,
                           __ATOMIC_RELAXED, __HIP_MEMORY_SCOPE_AGENT);
      }
    }

    // __syncthreads emits s_waitcnt vmcnt(0) per wave before s_barrier:
    // all write-through h stores are acked at the coherence point before
    // tid0 publishes the next-step flag/counter (relaxed agent store/RMW).
    __syncthreads();
    if (tid == 0) {
      if (MODE == 0) {
        __hip_atomic_store(sync + (size_t)(d * SLOTS + s + 1) * FLAGN + w, 1,
                           __ATOMIC_RELAXED, __HIP_MEMORY_SCOPE_AGENT);
      } else {
        __hip_atomic_fetch_add(sync + (size_t)(d * SLOTS + s + 1) * CSTRIDE, 1,
                               __ATOMIC_RELAXED, __HIP_MEMORY_SCOPE_AGENT);
      }
    }

    // out store AFTER publish: orderless wrt the sync protocol, drained by
    // the next step's barriers / kernel-end release.
    out[((size_t)cb * TDIM + tx) * (2 * HDIM) + d * HDIM + w * 8 + cj] = h;
  }
}

extern "C" void kernel_launch(void* const* d_in, const int* in_sizes, int n_in,
                              void* d_out, int out_size, void* d_ws, size_t ws_size,
                              hipStream_t stream) {
  const float* x    = (const float*)d_in[0];
  const float* WihF = (const float*)d_in[1];
  const float* WhhF = (const float*)d_in[2];
  const float* bihF = (const float*)d_in[3];
  const float* bhhF = (const float*)d_in[4];
  const float* WihB = (const float*)d_in[5];
  const float* WhhB = (const float*)d_in[6];
  const float* bihB = (const float*)d_in[7];
  const float* bhhB = (const float*)d_in[8];
  float* out = (float*)d_out;

  int* sync = (int*)d_ws;
  const size_t flag_bytes = (size_t)2 * SLOTS * FLAGN * 4;    // 262,656 B
  const size_t cnt_bytes  = (size_t)2 * SLOTS * CSTRIDE * 4;  // 65,664 B
  const size_t ring_payload = (size_t)SLOTS * 2 * SLICE_INTS * 4;
  const size_t ringF_bytes = flag_bytes + ring_payload;
  const size_t ringC_bytes = cnt_bytes + ring_payload;

  const int mode = (ws_size >= ringF_bytes) ? 0 : (ws_size >= ringC_bytes ? 1 : 2);
  int* hbuf = (int*)((char*)d_ws + (mode == 0 ? flag_bytes : cnt_bytes));
  const int nzero = (mode == 0) ? 2 * SLOTS * FLAGN : 2 * SLOTS * CSTRIDE;

  hipLaunchKernelGGL(init_ws_kernel, dim3(256), dim3(NTHR), 0, stream,
                     sync, hbuf, nzero);
  if (mode == 0) {
    hipLaunchKernelGGL((lstm_kernel<0>), dim3(2 * NWG), dim3(NTHR), 0, stream,
                       x, WihF, WhhF, bihF, bhhF, WihB, WhhB, bihB, bhhB,
                       out, sync, hbuf);
  } else if (mode == 1) {
    hipLaunchKernelGGL((lstm_kernel<1>), dim3(2 * NWG), dim3(NTHR), 0, stream,
                       x, WihF, WhhF, bihF, bhhF, WihB, WhhB, bihB, bhhB,
                       out, sync, hbuf);
  } else {
    hipLaunchKernelGGL((lstm_kernel<2>), dim3(2 * NWG), dim3(NTHR), 0, stream,
                       x, WihF, WhhF, bihF, bhhF, WihB, WhhB, bihB, bhhB,
                       out, sync, hbuf);
  }
}